// Round 1
// baseline (113.798 us; speedup 1.0000x reference)
//
#include <hip/hip_runtime.h>

// Problem constants (fixed shapes from setup_inputs)
constexpr int KK = 3;
constexpr int K2 = 9;          // KK*KK
constexpr int PADC = 1;        // (KK-1)/2
constexpr float DECAY = 4.0f;
constexpr float RELT = 0.3f;
constexpr float EPSV = 1e-8f;
constexpr int H = 480;
constexpr int W = 640;
constexpr int HW = H * W;

// Bilinear corner fetch with zero padding, matching the reference:
// clamp indices for the load, then zero out-of-bounds lanes.
__device__ __forceinline__ float dsample(const float* __restrict__ img, int iy, int ix) {
    bool valid = (iy >= 0) & (iy < H) & (ix >= 0) & (ix < W);
    int iyc = min(max(iy, 0), H - 1);
    int ixc = min(max(ix, 0), W - 1);
    float v = img[iyc * W + ixc];
    return valid ? v : 0.0f;
}

__global__ __launch_bounds__(256) void affinity_kernel(
    const float* __restrict__ depth,    // [B,1,H,W]
    const float* __restrict__ offset,   // [B,2*K2,H,W]
    float* __restrict__ out,            // [B,K2,H,W]
    int nquads)
{
    int idx = blockIdx.x * blockDim.x + threadIdx.x;
    if (idx >= nquads) return;

    int p = idx * 4;                 // first pixel of this thread's quad
    int b = p / HW;                  // compile-time-constant divisors -> magic mul
    int rem = p - b * HW;
    int y = rem / W;
    int x = rem - y * W;             // x, x+1, x+2, x+3 are on the same row (W%4==0)

    const float* __restrict__ dimg = depth + (size_t)b * HW;
    const float* __restrict__ offb = offset + ((size_t)b * 2 * K2) * HW + (size_t)y * W + x;

    float s[K2][4];
#pragma unroll
    for (int k = 0; k < K2; ++k) {
        const float4 oy = *reinterpret_cast<const float4*>(offb + (size_t)(2 * k) * HW);
        const float4 ox = *reinterpret_cast<const float4*>(offb + (size_t)(2 * k + 1) * HW);
        const float kyf = (float)(k / KK - PADC);
        const float kxf = (float)(k % KK - PADC);
        const float oys[4] = {oy.x, oy.y, oy.z, oy.w};
        const float oxs[4] = {ox.x, ox.y, ox.z, ox.w};
#pragma unroll
        for (int j = 0; j < 4; ++j) {
            float py = oys[j] + (float)y + kyf;
            float px = oxs[j] + (float)(x + j) + kxf;
            float y0f = floorf(py);
            float x0f = floorf(px);
            float wy = py - y0f;
            float wx = px - x0f;
            int y0 = (int)y0f;
            int x0 = (int)x0f;
            float v00 = dsample(dimg, y0, x0);
            float v01 = dsample(dimg, y0, x0 + 1);
            float v10 = dsample(dimg, y0 + 1, x0);
            float v11 = dsample(dimg, y0 + 1, x0 + 1);
            float wy1 = 1.0f - wy;
            float wx1 = 1.0f - wx;
            s[k][j] = v00 * wy1 * wx1 + v01 * wy1 * wx + v10 * wy * wx1 + v11 * wy * wx;
        }
    }

    float c[4], thr[4], cr[4];
#pragma unroll
    for (int j = 0; j < 4; ++j) {
        c[j] = s[K2 / 2][j];
        thr[j] = RELT * (c[j] + EPSV);   // diff <= 0.3*(c+eps)  <=>  diff/(c+eps) <= 0.3 (c>=0)
        cr[j] = RELT * c[j];
    }

    float* __restrict__ outb = out + ((size_t)b * K2) * HW + (size_t)y * W + x;
#pragma unroll
    for (int k = 0; k < K2; ++k) {
        float vals[4];
#pragma unroll
        for (int j = 0; j < 4; ++j) {
            float diff = fabsf(s[k][j] - c[j]);
            float aff = __expf(-DECAY * (diff - cr[j]));
            vals[j] = (diff <= thr[j]) ? 1.0f : aff;
        }
        float4 o = make_float4(vals[0], vals[1], vals[2], vals[3]);
        *reinterpret_cast<float4*>(outb + (size_t)k * HW) = o;
    }
}

extern "C" void kernel_launch(void* const* d_in, const int* in_sizes, int n_in,
                              void* d_out, int out_size, void* d_ws, size_t ws_size,
                              hipStream_t stream) {
    const float* depth = (const float*)d_in[0];
    const float* offset = (const float*)d_in[1];
    float* out = (float*)d_out;

    int B = in_sizes[0] / HW;          // depth is [B,1,H,W]
    int nquads = (B * HW) / 4;         // W % 4 == 0, HW % 4 == 0
    int threads = 256;
    int blocks = (nquads + threads - 1) / threads;
    affinity_kernel<<<blocks, threads, 0, stream>>>(depth, offset, out, nquads);
}

// Round 2
// 101.136 us; speedup vs baseline: 1.1252x; 1.1252x over previous
//
#include <hip/hip_runtime.h>

// Problem constants (fixed shapes from setup_inputs)
constexpr int KK = 3;
constexpr int K2 = 9;          // KK*KK
constexpr int PADC = 1;        // (KK-1)/2
constexpr float DECAY = 4.0f;
constexpr float RELT = 0.3f;
constexpr float EPSV = 1e-8f;
constexpr int H = 480;
constexpr int W = 640;
constexpr int HW = H * W;

// Bilinear corner fetch with zero padding, matching the reference:
// clamp indices for the load, then zero out-of-bounds lanes.
__device__ __forceinline__ float dsample(const float* __restrict__ img, int iy, int ix) {
    bool valid = (iy >= 0) & (iy < H) & (ix >= 0) & (ix < W);
    int iyc = min(max(iy, 0), H - 1);
    int ixc = min(max(ix, 0), W - 1);
    float v = img[iyc * W + ixc];
    return valid ? v : 0.0f;
}

__global__ __launch_bounds__(256) void affinity_kernel(
    const float* __restrict__ depth,    // [B,1,H,W]
    const float* __restrict__ offset,   // [B,2*K2,H,W]
    float* __restrict__ out,            // [B,K2,H,W]
    int npix)
{
    int idx = blockIdx.x * blockDim.x + threadIdx.x;
    if (idx >= npix) return;

    int b = idx / HW;                // compile-time-constant divisors -> magic mul
    int rem = idx - b * HW;
    int y = rem / W;
    int x = rem - y * W;             // lane i -> x+i : coalesced channel reads/writes

    const float* __restrict__ dimg = depth + (size_t)b * HW;
    const float* __restrict__ offp = offset + ((size_t)b * 2 * K2) * HW + (size_t)rem;

    // Load all 18 offset channels first (independent coalesced loads -> MLP)
    float oy[K2], ox[K2];
#pragma unroll
    for (int k = 0; k < K2; ++k) {
        oy[k] = offp[(size_t)(2 * k) * HW];
        ox[k] = offp[(size_t)(2 * k + 1) * HW];
    }

    float s[K2];
#pragma unroll
    for (int k = 0; k < K2; ++k) {
        float py = oy[k] + (float)(y + k / KK - PADC);
        float px = ox[k] + (float)(x + k % KK - PADC);
        float y0f = floorf(py);
        float x0f = floorf(px);
        float wy = py - y0f;
        float wx = px - x0f;
        int y0 = (int)y0f;
        int x0 = (int)x0f;
        float v00 = dsample(dimg, y0, x0);
        float v01 = dsample(dimg, y0, x0 + 1);
        float v10 = dsample(dimg, y0 + 1, x0);
        float v11 = dsample(dimg, y0 + 1, x0 + 1);
        float wy1 = 1.0f - wy;
        float wx1 = 1.0f - wx;
        s[k] = v00 * wy1 * wx1 + v01 * wy1 * wx + v10 * wy * wx1 + v11 * wy * wx;
    }

    float c = s[K2 / 2];
    float thr = RELT * (c + EPSV);   // diff <= 0.3*(c+eps)  <=>  diff/(c+eps) <= 0.3 (c>=0)
    float cr = RELT * c;

    float* __restrict__ outp = out + ((size_t)b * K2) * HW + (size_t)rem;
#pragma unroll
    for (int k = 0; k < K2; ++k) {
        float diff = fabsf(s[k] - c);
        float aff = __expf(-DECAY * (diff - cr));
        outp[(size_t)k * HW] = (diff <= thr) ? 1.0f : aff;
    }
}

extern "C" void kernel_launch(void* const* d_in, const int* in_sizes, int n_in,
                              void* d_out, int out_size, void* d_ws, size_t ws_size,
                              hipStream_t stream) {
    const float* depth = (const float*)d_in[0];
    const float* offset = (const float*)d_in[1];
    float* out = (float*)d_out;

    int npix = in_sizes[0];            // B * H * W (depth is [B,1,H,W])
    int threads = 256;
    int blocks = (npix + threads - 1) / threads;
    affinity_kernel<<<blocks, threads, 0, stream>>>(depth, offset, out, npix);
}

// Round 3
// 55.302 us; speedup vs baseline: 2.0577x; 1.8288x over previous
//
#include <hip/hip_runtime.h>

// Problem constants (fixed shapes from setup_inputs)
constexpr int KK = 3;
constexpr int K2 = 9;          // KK*KK
constexpr int PADC = 1;        // (KK-1)/2
constexpr float DECAY = 4.0f;
constexpr float RELT = 0.3f;
constexpr float EPSV = 1e-8f;
constexpr int H = 480;
constexpr int W = 640;
constexpr int HW = H * W;

// Tiling: each block produces an 8x64 tile of output pixels.
constexpr int TH = 8;
constexpr int TW = 64;
constexpr int PADT = 8;              // apron: N(0,1) offsets + kernel +-1 stay within +-8 in practice
constexpr int LR = TH + 2 * PADT;    // 24 staged rows
constexpr int LC = TW + 2 * PADT;    // 80 staged cols (valid)
constexpr int LSTRIDE = LC + 1;      // 81: odd stride de-phases LDS banks across rows
constexpr int NSTAGE = LR * LC;      // 1920 floats

// Global-path bilinear corner fetch with zero padding (rare fallback).
__device__ __forceinline__ float dsample(const float* __restrict__ img, int iy, int ix) {
    bool valid = (iy >= 0) & (iy < H) & (ix >= 0) & (ix < W);
    int iyc = min(max(iy, 0), H - 1);
    int ixc = min(max(ix, 0), W - 1);
    float v = img[iyc * W + ixc];
    return valid ? v : 0.0f;
}

__global__ __launch_bounds__(256) void affinity_kernel(
    const float* __restrict__ depth,    // [B,1,H,W]
    const float* __restrict__ offset,   // [B,2*K2,H,W]
    float* __restrict__ out)            // [B,K2,H,W]
{
    const int bx0 = blockIdx.x * TW;
    const int by0 = blockIdx.y * TH;
    const int b   = blockIdx.z;
    const int t   = threadIdx.x;

    __shared__ float tile[LR * LSTRIDE];

    const float* __restrict__ dimg = depth + (size_t)b * HW;

    // Stage depth apron into LDS with zero padding baked in (coalesced).
#pragma unroll
    for (int i = 0; i < (NSTAGE + 255) / 256; ++i) {
        int idx = t + i * 256;
        if (idx < NSTAGE) {
            int r = idx / LC;            // constant divisor
            int c = idx - r * LC;
            int yi = by0 - PADT + r;
            int xi = bx0 - PADT + c;
            float v = 0.0f;
            if ((unsigned)yi < (unsigned)H && (unsigned)xi < (unsigned)W)
                v = dimg[yi * W + xi];
            tile[r * LSTRIDE + c] = v;
        }
    }
    __syncthreads();

    const int c  = t & 63;               // lane -> consecutive x: coalesced channel I/O
    const int r0 = t >> 6;               // 0..3

#pragma unroll
    for (int pi = 0; pi < 2; ++pi) {
        const int r = r0 + pi * 4;       // 0..7
        const int y = by0 + r;
        const int x = bx0 + c;

        const size_t base = ((size_t)b * 2 * K2) * HW + (size_t)y * W + x;
        float oy[K2], ox[K2];
#pragma unroll
        for (int k = 0; k < K2; ++k) {
            oy[k] = offset[base + (size_t)(2 * k) * HW];
            ox[k] = offset[base + (size_t)(2 * k + 1) * HW];
        }

        float s[K2];
#pragma unroll
        for (int k = 0; k < K2; ++k) {
            // tile-relative coords: pyt = py - (by0 - PADT)
            float pyt = oy[k] + (float)(r + PADT + k / KK - PADC);
            float pxt = ox[k] + (float)(c + PADT + k % KK - PADC);
            float y0f = floorf(pyt);
            float x0f = floorf(pxt);
            float wy = pyt - y0f;
            float wx = pxt - x0f;
            int y0 = (int)y0f;
            int x0 = (int)x0f;
            float v00, v01, v10, v11;
            if ((unsigned)y0 < (unsigned)(LR - 1) && (unsigned)x0 < (unsigned)(LC - 1)) {
                // fast path: zeros already staged for out-of-image texels
                int a = y0 * LSTRIDE + x0;
                v00 = tile[a];
                v01 = tile[a + 1];
                v10 = tile[a + LSTRIDE];
                v11 = tile[a + LSTRIDE + 1];
            } else {
                // rare fallback for samples outside the apron
                int gy = y0 + by0 - PADT;
                int gx = x0 + bx0 - PADT;
                v00 = dsample(dimg, gy, gx);
                v01 = dsample(dimg, gy, gx + 1);
                v10 = dsample(dimg, gy + 1, gx);
                v11 = dsample(dimg, gy + 1, gx + 1);
            }
            float wy1 = 1.0f - wy;
            float wx1 = 1.0f - wx;
            s[k] = v00 * wy1 * wx1 + v01 * wy1 * wx + v10 * wy * wx1 + v11 * wy * wx;
        }

        const float cv  = s[K2 / 2];
        const float thr = RELT * (cv + EPSV);  // diff/(c+eps)<=0.3 <=> diff<=0.3*(c+eps), c>=0
        const float cr  = RELT * cv;

        const size_t obase = ((size_t)b * K2) * HW + (size_t)y * W + x;
#pragma unroll
        for (int k = 0; k < K2; ++k) {
            float diff = fabsf(s[k] - cv);
            float aff = __expf(-DECAY * (diff - cr));
            out[obase + (size_t)k * HW] = (diff <= thr) ? 1.0f : aff;
        }
    }
}

extern "C" void kernel_launch(void* const* d_in, const int* in_sizes, int n_in,
                              void* d_out, int out_size, void* d_ws, size_t ws_size,
                              hipStream_t stream) {
    const float* depth = (const float*)d_in[0];
    const float* offset = (const float*)d_in[1];
    float* out = (float*)d_out;

    int B = in_sizes[0] / HW;          // depth is [B,1,H,W]
    dim3 grid(W / TW, H / TH, B);      // 10 x 60 x B
    affinity_kernel<<<grid, 256, 0, stream>>>(depth, offset, out);
}

// Round 5
// 49.652 us; speedup vs baseline: 2.2919x; 1.1138x over previous
//
#include <hip/hip_runtime.h>

// Problem constants (fixed shapes from setup_inputs)
constexpr int KK = 3;
constexpr int K2 = 9;          // KK*KK
constexpr int PADC = 1;        // (KK-1)/2
constexpr float DECAY = 4.0f;
constexpr float RELT = 0.3f;
constexpr float EPSV = 1e-8f;
constexpr int H = 480;
constexpr int W = 640;
constexpr int HW = H * W;

typedef float f32x4 __attribute__((ext_vector_type(4)));   // native vector: ok for nontemporal builtins

// Tiling: each block produces a 16x64 tile; 256 threads x 4 px (float4 I/O).
constexpr int TH = 16;
constexpr int TW = 64;
constexpr int PADT = 8;              // apron: N(0,1) offsets + kernel +-1 stay within +-8 in practice
constexpr int LR = TH + 2 * PADT;    // 32 staged rows
constexpr int LC = TW + 2 * PADT;    // 80 staged cols (valid)
constexpr int LSTRIDE = LC + 1;      // 81: odd stride de-phases LDS banks across rows
constexpr int NSTAGE = LR * LC;      // 2560 = 10 * 256 exactly

// Global-path bilinear corner fetch with zero padding (rare fallback).
__device__ __forceinline__ float dsample(const float* __restrict__ img, int iy, int ix) {
    bool valid = (iy >= 0) & (iy < H) & (ix >= 0) & (ix < W);
    int iyc = min(max(iy, 0), H - 1);
    int ixc = min(max(ix, 0), W - 1);
    float v = img[iyc * W + ixc];
    return valid ? v : 0.0f;
}

// One bilinear tap for 4 consecutive pixels; returns samples in s4[0..3].
__device__ __forceinline__ void tap4(const float* __restrict__ tile,
                                     const float* __restrict__ dimg,
                                     int by0, int bx0, int r, int col,
                                     f32x4 oy, f32x4 ox, int ky, int kx,
                                     float* s4) {
#pragma unroll
    for (int j = 0; j < 4; ++j) {
        float pyt = oy[j] + (float)(r + PADT + ky);
        float pxt = ox[j] + (float)(col + j + PADT + kx);
        float y0f = floorf(pyt);
        float x0f = floorf(pxt);
        float wy = pyt - y0f;
        float wx = pxt - x0f;
        int y0 = (int)y0f;
        int x0 = (int)x0f;
        float v00, v01, v10, v11;
        if ((unsigned)y0 < (unsigned)(LR - 1) && (unsigned)x0 < (unsigned)(LC - 1)) {
            int a = y0 * LSTRIDE + x0;
            v00 = tile[a];
            v01 = tile[a + 1];
            v10 = tile[a + LSTRIDE];
            v11 = tile[a + LSTRIDE + 1];
        } else {
            int gy = y0 + by0 - PADT;
            int gx = x0 + bx0 - PADT;
            v00 = dsample(dimg, gy, gx);
            v01 = dsample(dimg, gy, gx + 1);
            v10 = dsample(dimg, gy + 1, gx);
            v11 = dsample(dimg, gy + 1, gx + 1);
        }
        float wy1 = 1.0f - wy;
        float wx1 = 1.0f - wx;
        s4[j] = v00 * wy1 * wx1 + v01 * wy1 * wx + v10 * wy * wx1 + v11 * wy * wx;
    }
}

__global__ __launch_bounds__(256) void affinity_kernel(
    const float* __restrict__ depth,    // [B,1,H,W]
    const float* __restrict__ offset,   // [B,2*K2,H,W]
    float* __restrict__ out)            // [B,K2,H,W]
{
    const int bx0 = blockIdx.x * TW;
    const int by0 = blockIdx.y * TH;
    const int b   = blockIdx.z;
    const int t   = threadIdx.x;

    __shared__ float tile[LR * LSTRIDE];

    const float* __restrict__ dimg = depth + (size_t)b * HW;

    // Stage depth apron into LDS with zero padding baked in (coalesced, exact fit).
#pragma unroll
    for (int i = 0; i < NSTAGE / 256; ++i) {
        int idx = t + i * 256;
        int r = idx / LC;                // constant divisor
        int c = idx - r * LC;
        int yi = by0 - PADT + r;
        int xi = bx0 - PADT + c;
        float v = 0.0f;
        if ((unsigned)yi < (unsigned)H && (unsigned)xi < (unsigned)W)
            v = dimg[yi * W + xi];
        tile[r * LSTRIDE + c] = v;
    }
    __syncthreads();

    const int col = (t & 15) * 4;        // 4 consecutive x per thread (16B aligned)
    const int r   = t >> 4;              // 0..15
    const int y   = by0 + r;
    const int x   = bx0 + col;

    const size_t obase = ((size_t)b * 2 * K2) * HW + (size_t)y * W + x;
    const float* __restrict__ offp = offset + obase;

    // Center tap first (k = 4): gives c for all channels; its own output is 1.0.
    float c4[4];
    {
        f32x4 oy = *reinterpret_cast<const f32x4*>(offp + (size_t)8 * HW);
        f32x4 ox = *reinterpret_cast<const f32x4*>(offp + (size_t)9 * HW);
        tap4(tile, dimg, by0, bx0, r, col, oy, ox, 0, 0, c4);
    }
    float thr[4], cr[4];
#pragma unroll
    for (int j = 0; j < 4; ++j) {
        thr[j] = RELT * (c4[j] + EPSV);  // diff/(c+eps)<=0.3 <=> diff<=0.3*(c+eps), c>=0
        cr[j]  = RELT * c4[j];
    }

    float* __restrict__ outp = out + ((size_t)b * K2) * HW + (size_t)y * W + x;

    // Center channel output is identically 1.0 (diff = 0 <= thr).
    {
        f32x4 ones = {1.0f, 1.0f, 1.0f, 1.0f};
        __builtin_nontemporal_store(ones, reinterpret_cast<f32x4*>(outp + (size_t)4 * HW));
    }

#pragma unroll
    for (int k = 0; k < K2; ++k) {
        if (k == 4) continue;
        f32x4 oy = *reinterpret_cast<const f32x4*>(offp + (size_t)(2 * k) * HW);
        f32x4 ox = *reinterpret_cast<const f32x4*>(offp + (size_t)(2 * k + 1) * HW);
        float s4[4];
        tap4(tile, dimg, by0, bx0, r, col, oy, ox, k / KK - PADC, k % KK - PADC, s4);
        f32x4 vals;
#pragma unroll
        for (int j = 0; j < 4; ++j) {
            float diff = fabsf(s4[j] - c4[j]);
            float aff = __expf(-DECAY * (diff - cr[j]));
            vals[j] = (diff <= thr[j]) ? 1.0f : aff;
        }
        __builtin_nontemporal_store(vals, reinterpret_cast<f32x4*>(outp + (size_t)k * HW));
    }
}

extern "C" void kernel_launch(void* const* d_in, const int* in_sizes, int n_in,
                              void* d_out, int out_size, void* d_ws, size_t ws_size,
                              hipStream_t stream) {
    const float* depth = (const float*)d_in[0];
    const float* offset = (const float*)d_in[1];
    float* out = (float*)d_out;

    int B = in_sizes[0] / HW;          // depth is [B,1,H,W]
    dim3 grid(W / TW, H / TH, B);      // 10 x 30 x B
    affinity_kernel<<<grid, 256, 0, stream>>>(depth, offset, out);
}